// Round 4
// baseline (502.229 us; speedup 1.0000x reference)
//
#include <hip/hip_runtime.h>
#include <math.h>

#define GLN_EPS 1e-6f
#define CCH 256                 // channels (fixed by problem)
#define C4 (CCH / 4)            // 64 float4 per row == one wave

// ---------------- K1: per-graph stats (pure read stream) ----------------
#define NW1 16
#define BLK1 (NW1 * 64)         // 1024 threads -> 2 blocks/CU * 16 waves = 32 waves/CU

__device__ __forceinline__ float wave_reduce_sum(float x) {
#pragma unroll
    for (int off = 32; off > 0; off >>= 1) x += __shfl_xor(x, off);
    return x;
}

__global__ void __launch_bounds__(BLK1, 8) stats_kernel(
    const float* __restrict__ s, const float* __restrict__ v,
    const int* __restrict__ splits,
    float* __restrict__ mgws,      // [G*C]  per-graph per-channel mean (centered)
    float* __restrict__ rstds,     // [G]
    float* __restrict__ rvns,      // [G]
    float* __restrict__ rowmean,   // [N]    per-node channel mean
    int*   __restrict__ seg)       // [N]    node -> graph id
{
    __shared__ float4 csum_part[NW1][C4];   // 16 KB
    __shared__ float  red[NW1][3];
    __shared__ int    ired[NW1];

    const int tid  = threadIdx.x;
    const int wv   = tid >> 6;
    const int lane = tid & 63;
    const int g    = blockIdx.x;

    // start offset = prefix sum of splits[0..g)
    int acc = 0;
    for (int i = tid; i < g; i += BLK1) acc += splits[i];
#pragma unroll
    for (int off = 32; off > 0; off >>= 1) acc += __shfl_xor(acc, off);
    if (lane == 0) ired[wv] = acc;
    __syncthreads();
    int start = 0;
#pragma unroll
    for (int i = 0; i < NW1; i++) start += ired[i];
    const int cnt = splits[g];
    if (cnt <= 0) return;
    const float inv_cnt  = 1.0f / (float)cnt;
    const float inv_C    = 1.0f / (float)CCH;
    const float inv_cntC = inv_cnt * inv_C;

    const float4* s4p = (const float4*)s;
    const float4* v4p = (const float4*)v;

    float4 colsum = make_float4(0.f, 0.f, 0.f, 0.f);
    float sumsq = 0.f, rs2 = 0.f, vn = 0.f;

    for (int rr = wv; rr < cnt; rr += NW1) {
        const size_t row = (size_t)(start + rr);
        float4 sv = s4p[row * C4 + lane];
        colsum.x += sv.x; colsum.y += sv.y; colsum.z += sv.z; colsum.w += sv.w;
        sumsq = fmaf(sv.x, sv.x, sumsq);
        sumsq = fmaf(sv.y, sv.y, sumsq);
        sumsq = fmaf(sv.z, sv.z, sumsq);
        sumsq = fmaf(sv.w, sv.w, sumsq);
        float rsum = wave_reduce_sum(sv.x + sv.y + sv.z + sv.w);
        if (lane == 0) {
            rs2 = fmaf(rsum, rsum, rs2);
            rowmean[row] = rsum * inv_C;     // K2 reads this: no shuffles in K2
            seg[row]     = g;                // K2 reads this: no prefix-sum in K2
        }

        const size_t vb = row * (3 * C4) + lane;
        float4 a  = v4p[vb];
        float4 bq = v4p[vb + C4];
        float4 cq = v4p[vb + 2 * C4];
        // vn_tot is a flat sum over rows*channels: lane-local accumulate, no per-row reduce
        vn += sqrtf(fmaf(a.x, a.x, fmaf(bq.x, bq.x, cq.x * cq.x)) + GLN_EPS);
        vn += sqrtf(fmaf(a.y, a.y, fmaf(bq.y, bq.y, cq.y * cq.y)) + GLN_EPS);
        vn += sqrtf(fmaf(a.z, a.z, fmaf(bq.z, bq.z, cq.z * cq.z)) + GLN_EPS);
        vn += sqrtf(fmaf(a.w, a.w, fmaf(bq.w, bq.w, cq.w * cq.w)) + GLN_EPS);
    }
    csum_part[wv][lane] = colsum;

    float t0 = wave_reduce_sum(sumsq);
    float t1 = wave_reduce_sum(rs2);
    float t2 = wave_reduce_sum(vn);
    if (lane == 0) { red[wv][0] = t0; red[wv][1] = t1; red[wv][2] = t2; }
    __syncthreads();

    if (wv == 0) {
        float sumsq_tot = 0.f, rs2_tot = 0.f, vn_tot = 0.f;
#pragma unroll
        for (int i = 0; i < NW1; i++) {
            sumsq_tot += red[i][0]; rs2_tot += red[i][1]; vn_tot += red[i][2];
        }
        float4 t = csum_part[0][lane];
#pragma unroll
        for (int i = 1; i < NW1; i++) {
            t.x += csum_part[i][lane].x; t.y += csum_part[i][lane].y;
            t.z += csum_part[i][lane].z; t.w += csum_part[i][lane].w;
        }
        float gsum  = wave_reduce_sum(t.x + t.y + t.z + t.w);
        float gmean = gsum * inv_cntC;
        float4 mg;
        mg.x = t.x * inv_cnt - gmean;
        mg.y = t.y * inv_cnt - gmean;
        mg.z = t.z * inv_cnt - gmean;
        mg.w = t.w * inv_cnt - gmean;
        ((float4*)mgws)[(size_t)g * C4 + lane] = mg;
        float mg2 = wave_reduce_sum(mg.x * mg.x + mg.y * mg.y + mg.z * mg.z + mg.w * mg.w);
        if (lane == 0) {
            const float sum_s0sq = sumsq_tot - rs2_tot * inv_C;
            const float sum_cs2  = sum_s0sq - (float)cnt * mg2;
            const float var      = sum_cs2 * inv_cntC;
            rstds[g] = 1.0f / sqrtf(var + GLN_EPS);
            rvns[g]  = 1.0f / (vn_tot * inv_cntC);
        }
    }
}

// ---------------- K2: apply (pure grid-stride stream, no barriers/shuffles) ----------------
#define BLK2 256
#define NW2 (BLK2 / 64)

__global__ void __launch_bounds__(BLK2, 8) apply_kernel(
    const float* __restrict__ s, const float* __restrict__ v,
    const float* __restrict__ weight, const float* __restrict__ bias,
    const float* __restrict__ mgws, const float* __restrict__ rstds,
    const float* __restrict__ rvns, const float* __restrict__ rowmean,
    const int* __restrict__ seg,
    float* __restrict__ sout, float* __restrict__ vout, int N)
{
    const int lane   = threadIdx.x & 63;
    int       n      = blockIdx.x * NW2 + (threadIdx.x >> 6);
    const int stride = gridDim.x * NW2;

    const float4 w4 = ((const float4*)weight)[lane];
    const float4 b4 = ((const float4*)bias)[lane];
    const float4* s4p  = (const float4*)s;
    const float4* v4p  = (const float4*)v;
    const float4* mg4p = (const float4*)mgws;
    float4* so4 = (float4*)sout;
    float4* vo4 = (float4*)vout;

    for (; n < N; n += stride) {
        const int   gg    = seg[n];
        const float rmean = rowmean[n];
        const float rstd  = rstds[gg];
        const float rvn   = rvns[gg];
        const float4 mg   = mg4p[(size_t)gg * C4 + lane];

        const float4 sv = s4p[(size_t)n * C4 + lane];
        const size_t vb = (size_t)n * (3 * C4) + lane;
        float4 a  = v4p[vb];
        float4 bq = v4p[vb + C4];
        float4 cq = v4p[vb + 2 * C4];

        float4 o;
        o.x = fmaf((sv.x - rmean - mg.x) * rstd, w4.x, b4.x);
        o.y = fmaf((sv.y - rmean - mg.y) * rstd, w4.y, b4.y);
        o.z = fmaf((sv.z - rmean - mg.z) * rstd, w4.z, b4.z);
        o.w = fmaf((sv.w - rmean - mg.w) * rstd, w4.w, b4.w);
        so4[(size_t)n * C4 + lane] = o;

        a.x  *= rvn; a.y  *= rvn; a.z  *= rvn; a.w  *= rvn;
        bq.x *= rvn; bq.y *= rvn; bq.z *= rvn; bq.w *= rvn;
        cq.x *= rvn; cq.y *= rvn; cq.z *= rvn; cq.w *= rvn;
        vo4[vb]          = a;
        vo4[vb + C4]     = bq;
        vo4[vb + 2 * C4] = cq;
    }
}

extern "C" void kernel_launch(void* const* d_in, const int* in_sizes, int n_in,
                              void* d_out, int out_size, void* d_ws, size_t ws_size,
                              hipStream_t stream) {
    const float* s      = (const float*)d_in[0];
    const float* v      = (const float*)d_in[1];
    const float* w      = (const float*)d_in[2];
    const float* b      = (const float*)d_in[3];
    const int*   splits = (const int*)d_in[4];
    const int N = in_sizes[0] / CCH;
    const int G = in_sizes[4];
    float* out  = (float*)d_out;
    float* sout = out;
    float* vout = out + (size_t)N * CCH;

    // workspace layout (floats): mg[G*C] | rstd[G] | rvn[G] | rowmean[N] | seg[N](int)
    float* wsf     = (float*)d_ws;
    float* mgws    = wsf;
    float* rstds   = wsf + (size_t)G * CCH;
    float* rvns    = rstds + G;
    float* rowmean = rvns + G;
    int*   seg     = (int*)(rowmean + N);

    stats_kernel<<<G, BLK1, 0, stream>>>(s, v, splits, mgws, rstds, rvns, rowmean, seg);

    int grid2 = 2048;
    int total_waves_needed = (N + 0) ;  // one node per wave per iter; grid-stride covers any N
    (void)total_waves_needed;
    apply_kernel<<<grid2, BLK2, 0, stream>>>(s, v, w, b, mgws, rstds, rvns, rowmean, seg,
                                             sout, vout, N);
}

// Round 5
// 480.461 us; speedup vs baseline: 1.0453x; 1.0453x over previous
//
#include <hip/hip_runtime.h>
#include <math.h>

#define GLN_EPS 1e-6f
#define NW 8                    // waves per block
#define BLOCK (NW * 64)         // 512 threads
#define CCH 256                 // channels (fixed by problem)
#define C4 (CCH / 4)            // 64 float4 per row == one wave
#define RPW 16                  // rows per wave, fast path (cnt == NW*RPW == 128)
#define RCAP 2048               // rowmean cache rows (generic path)

__device__ __forceinline__ float wave_reduce_sum(float x) {
#pragma unroll
    for (int off = 32; off > 0; off >>= 1) x += __shfl_xor(x, off);
    return x;
}

__global__ void __launch_bounds__(BLOCK, 4) gln_kernel(
    const float* __restrict__ s, const float* __restrict__ v,
    const float* __restrict__ weight, const float* __restrict__ bias,
    const int* __restrict__ splits,
    float* __restrict__ sout, float* __restrict__ vout)
{
    __shared__ float4 csum_part[NW][C4];   // 8 KB
    __shared__ float4 mg4[C4];             // 1 KB
    __shared__ float4 w4s[C4];             // 1 KB
    __shared__ float4 b4s[C4];             // 1 KB
    __shared__ float  rowmean_s[RCAP];     // 8 KB
    __shared__ float  red[NW][3];
    __shared__ int    ired[NW];
    __shared__ float  s_mg2;

    const int tid  = threadIdx.x;
    const int wv   = tid >> 6;
    const int lane = tid & 63;
    const int g    = blockIdx.x;

    // ---- start offset = prefix sum of splits[0..g) ----
    int acc = 0;
    for (int i = tid; i < g; i += BLOCK) acc += splits[i];
#pragma unroll
    for (int off = 32; off > 0; off >>= 1) acc += __shfl_xor(acc, off);
    if (lane == 0) ired[wv] = acc;
    if (wv == 0) {
        w4s[lane] = ((const float4*)weight)[lane];
        b4s[lane] = ((const float4*)bias)[lane];
    }
    __syncthreads();
    int start = 0;
#pragma unroll
    for (int i = 0; i < NW; i++) start += ired[i];
    const int cnt = splits[g];
    if (cnt <= 0) return;
    const float inv_cnt  = 1.0f / (float)cnt;
    const float inv_C    = 1.0f / (float)CCH;
    const float inv_cntC = inv_cnt * inv_C;

    const float4* s4p = (const float4*)s;
    const float4* v4p = (const float4*)v;

    const bool fast = (cnt == NW * RPW);

    // ---- pass A: accumulate stats ----
    float4 colsum = make_float4(0.f, 0.f, 0.f, 0.f);
    float sumsq = 0.f, rs2 = 0.f, vn = 0.f;

    if (fast) {
        const int rbase = start + wv * RPW;   // contiguous 16-row span per wave
        float prow[RPW];                      // per-lane partial rowsums (registers)

        // s stream: pure loads + lane-local math. ZERO cross-lane ops.
#pragma unroll 4
        for (int k = 0; k < RPW; k++) {
            const size_t row = (size_t)(rbase + k);
            float4 sv = s4p[row * C4 + lane];
            colsum.x += sv.x; colsum.y += sv.y; colsum.z += sv.z; colsum.w += sv.w;
            sumsq = fmaf(sv.x, sv.x, sumsq);
            sumsq = fmaf(sv.y, sv.y, sumsq);
            sumsq = fmaf(sv.z, sv.z, sumsq);
            sumsq = fmaf(sv.w, sv.w, sumsq);
            prow[k] = sv.x + sv.y + sv.z + sv.w;
        }
        // v stream: lane-local accumulate (vn_tot is a flat sum). ZERO cross-lane ops.
#pragma unroll 4
        for (int k = 0; k < RPW; k++) {
            const size_t row = (size_t)(rbase + k);
            const size_t vb  = row * (3 * C4) + lane;
            float4 a  = v4p[vb];
            float4 bq = v4p[vb + C4];
            float4 cq = v4p[vb + 2 * C4];
            vn += sqrtf(fmaf(a.x, a.x, fmaf(bq.x, bq.x, cq.x * cq.x)) + GLN_EPS);
            vn += sqrtf(fmaf(a.y, a.y, fmaf(bq.y, bq.y, cq.y * cq.y)) + GLN_EPS);
            vn += sqrtf(fmaf(a.z, a.z, fmaf(bq.z, bq.z, cq.z * cq.z)) + GLN_EPS);
            vn += sqrtf(fmaf(a.w, a.w, fmaf(bq.w, bq.w, cq.w * cq.w)) + GLN_EPS);
        }

        // phase B (off the load path): 16 INDEPENDENT register-fed shuffle chains,
        // throughput-bound with cross-row ILP instead of latency-bound in-stream.
#pragma unroll
        for (int k = 0; k < RPW; k++) {
            float rsum = wave_reduce_sum(prow[k]);
            if (lane == 0) {
                rowmean_s[wv * RPW + k] = rsum * inv_C;
                rs2 = fmaf(rsum, rsum, rs2);
            }
        }
    } else {
        for (int rr = wv; rr < cnt; rr += NW) {
            const size_t row = (size_t)(start + rr);
            float4 sv = s4p[row * C4 + lane];
            colsum.x += sv.x; colsum.y += sv.y; colsum.z += sv.z; colsum.w += sv.w;
            sumsq = fmaf(sv.x, sv.x, sumsq);
            sumsq = fmaf(sv.y, sv.y, sumsq);
            sumsq = fmaf(sv.z, sv.z, sumsq);
            sumsq = fmaf(sv.w, sv.w, sumsq);
            float rsum = wave_reduce_sum(sv.x + sv.y + sv.z + sv.w);
            if (lane == 0) {
                rs2 = fmaf(rsum, rsum, rs2);
                if (rr < RCAP) rowmean_s[rr] = rsum * inv_C;
            }
            const size_t vb = row * (3 * C4) + lane;
            float4 a  = v4p[vb];
            float4 bq = v4p[vb + C4];
            float4 cq = v4p[vb + 2 * C4];
            vn += sqrtf(fmaf(a.x, a.x, fmaf(bq.x, bq.x, cq.x * cq.x)) + GLN_EPS);
            vn += sqrtf(fmaf(a.y, a.y, fmaf(bq.y, bq.y, cq.y * cq.y)) + GLN_EPS);
            vn += sqrtf(fmaf(a.z, a.z, fmaf(bq.z, bq.z, cq.z * cq.z)) + GLN_EPS);
            vn += sqrtf(fmaf(a.w, a.w, fmaf(bq.w, bq.w, cq.w * cq.w)) + GLN_EPS);
        }
    }
    csum_part[wv][lane] = colsum;

    // ---- block-reduce the three scalars ----
    float t0 = wave_reduce_sum(sumsq);
    float t2 = wave_reduce_sum(vn);
    if (lane == 0) { red[wv][0] = t0; red[wv][1] = rs2; red[wv][2] = t2; }
    __syncthreads();

    // ---- wave 0: per-channel graph mean + final scalars ----
    if (wv == 0) {
        float sumsq_tot = 0.f, rs2_tot = 0.f, vn_tot = 0.f;
#pragma unroll
        for (int i = 0; i < NW; i++) {
            sumsq_tot += red[i][0]; rs2_tot += red[i][1]; vn_tot += red[i][2];
        }
        float4 t = csum_part[0][lane];
#pragma unroll
        for (int i = 1; i < NW; i++) {
            t.x += csum_part[i][lane].x; t.y += csum_part[i][lane].y;
            t.z += csum_part[i][lane].z; t.w += csum_part[i][lane].w;
        }
        float gsum  = wave_reduce_sum(t.x + t.y + t.z + t.w);
        float gmean = gsum * inv_cntC;
        float4 mg;
        mg.x = t.x * inv_cnt - gmean;
        mg.y = t.y * inv_cnt - gmean;
        mg.z = t.z * inv_cnt - gmean;
        mg.w = t.w * inv_cnt - gmean;
        mg4[lane] = mg;
        float mg2 = wave_reduce_sum(mg.x * mg.x + mg.y * mg.y + mg.z * mg.z + mg.w * mg.w);
        if (lane == 0) {
            const float sum_s0sq = sumsq_tot - rs2_tot * inv_C;
            const float sum_cs2  = sum_s0sq - (float)cnt * mg2;
            const float var      = sum_cs2 * inv_cntC;
            red[0][0] = 1.0f / sqrtf(var + GLN_EPS);          // rstd
            red[0][1] = 1.0f / (vn_tot * inv_cntC);           // rvn
            s_mg2 = 0.f;                                      // (unused marker)
        }
    }
    __syncthreads();

    const float rstd = red[0][0];
    const float rvn  = red[0][1];

    // ---- pass C: outputs. Pure stream, zero cross-lane ops (fast path). ----
    float4 wl = w4s[lane];
    wl.x *= rstd; wl.y *= rstd; wl.z *= rstd; wl.w *= rstd;
    const float4 bl = b4s[lane];
    const float4 mg = mg4[lane];
    float4* so4 = (float4*)sout;
    float4* vo4 = (float4*)vout;

    if (fast) {
        const int rbase = start + wv * RPW;
#pragma unroll 4
        for (int k = 0; k < RPW; k++) {
            const size_t row = (size_t)(rbase + k);
            const float rmean = rowmean_s[wv * RPW + k];   // LDS broadcast
            float4 sv = s4p[row * C4 + lane];              // L3-warm re-read
            float4 o;
            o.x = fmaf(sv.x - rmean - mg.x, wl.x, bl.x);
            o.y = fmaf(sv.y - rmean - mg.y, wl.y, bl.y);
            o.z = fmaf(sv.z - rmean - mg.z, wl.z, bl.z);
            o.w = fmaf(sv.w - rmean - mg.w, wl.w, bl.w);
            so4[row * C4 + lane] = o;
        }
#pragma unroll 2
        for (int k = 0; k < RPW; k++) {
            const size_t row = (size_t)(rbase + k);
            const size_t vb  = row * (3 * C4) + lane;
            float4 a  = v4p[vb];
            float4 bq = v4p[vb + C4];
            float4 cq = v4p[vb + 2 * C4];
            a.x  *= rvn; a.y  *= rvn; a.z  *= rvn; a.w  *= rvn;
            bq.x *= rvn; bq.y *= rvn; bq.z *= rvn; bq.w *= rvn;
            cq.x *= rvn; cq.y *= rvn; cq.z *= rvn; cq.w *= rvn;
            vo4[vb]          = a;
            vo4[vb + C4]     = bq;
            vo4[vb + 2 * C4] = cq;
        }
    } else {
        for (int rr = wv; rr < cnt; rr += NW) {
            const size_t row = (size_t)(start + rr);
            float4 sv = s4p[row * C4 + lane];
            float rmean;
            if (rr < RCAP) {
                rmean = rowmean_s[rr];
            } else {
                rmean = wave_reduce_sum(sv.x + sv.y + sv.z + sv.w) * inv_C;
            }
            float4 o;
            o.x = fmaf(sv.x - rmean - mg.x, wl.x, bl.x);
            o.y = fmaf(sv.y - rmean - mg.y, wl.y, bl.y);
            o.z = fmaf(sv.z - rmean - mg.z, wl.z, bl.z);
            o.w = fmaf(sv.w - rmean - mg.w, wl.w, bl.w);
            so4[row * C4 + lane] = o;

            const size_t vb = row * (3 * C4) + lane;
            float4 a  = v4p[vb];
            float4 bq = v4p[vb + C4];
            float4 cq = v4p[vb + 2 * C4];
            a.x  *= rvn; a.y  *= rvn; a.z  *= rvn; a.w  *= rvn;
            bq.x *= rvn; bq.y *= rvn; bq.z *= rvn; bq.w *= rvn;
            cq.x *= rvn; cq.y *= rvn; cq.z *= rvn; cq.w *= rvn;
            vo4[vb]          = a;
            vo4[vb + C4]     = bq;
            vo4[vb + 2 * C4] = cq;
        }
    }
}

extern "C" void kernel_launch(void* const* d_in, const int* in_sizes, int n_in,
                              void* d_out, int out_size, void* d_ws, size_t ws_size,
                              hipStream_t stream) {
    const float* s      = (const float*)d_in[0];
    const float* v      = (const float*)d_in[1];
    const float* w      = (const float*)d_in[2];
    const float* b      = (const float*)d_in[3];
    const int*   splits = (const int*)d_in[4];
    const int N = in_sizes[0] / CCH;
    const int G = in_sizes[4];
    float* out  = (float*)d_out;
    float* sout = out;
    float* vout = out + (size_t)N * CCH;
    gln_kernel<<<G, BLOCK, 0, stream>>>(s, v, w, b, splits, sout, vout);
}